// Round 1
// baseline (238.340 us; speedup 1.0000x reference)
//
#include <hip/hip_runtime.h>

#define K_CLS 64
#define DIM   256
#define TPB   1024
#define WAVES (TPB / 64)
#define NBLK_MAX 256

// ---------------------------------------------------------------------------
// Pass 1: per-block partial {sums[K][D], sumsq[K], count[K]} via LDS atomics.
// LDS sum layout is XOR-swizzled within each class row: value of dim d stored
// at index d ^ ((d>>5)&3), which makes each of the 4 per-lane ds_add_f32
// instructions hit 32 banks at 2 lanes/bank (conflict-free on CDNA4).
// ---------------------------------------------------------------------------
__global__ __launch_bounds__(TPB) void fstat_pass1(
    const float* __restrict__ z, const int* __restrict__ c,
    float* __restrict__ psums, float* __restrict__ pcnt, float* __restrict__ psq,
    int N, int P, int nblk)
{
    __shared__ float lds_sq[K_CLS * 64];   // per-(class, lane) sq partials, 16 KB
    __shared__ float lds_cnt[K_CLS];       // per-class counts
    __shared__ float lds_sum[K_CLS * DIM]; // swizzled per-class sums, 64 KB

    const int t = threadIdx.x;

    for (int i = t; i < K_CLS * DIM; i += TPB) lds_sum[i] = 0.f;
    for (int i = t; i < K_CLS * 64; i += TPB)  lds_sq[i]  = 0.f;
    if (t < K_CLS) lds_cnt[t] = 0.f;
    __syncthreads();

    const int wave = t >> 6;
    const int lane = t & 63;
    const int gw   = blockIdx.x * WAVES + wave;   // global wave id
    const int TW   = nblk * WAVES;                // total waves
    const int s    = (lane >> 3) & 3;             // swizzle selector
    const int o0   = 4 * lane + (0 ^ s);
    const int o1   = 4 * lane + (1 ^ s);
    const int o2   = 4 * lane + (2 ^ s);
    const int o3   = 4 * lane + (3 ^ s);

    auto body = [&](int r) {
        float4 v = reinterpret_cast<const float4*>(z)[(size_t)r * (DIM / 4) + lane];
        int cls = c[r];                       // wave-uniform
        int cb  = cls * DIM;
        atomicAdd(&lds_sum[cb + o0], v.x);
        atomicAdd(&lds_sum[cb + o1], v.y);
        atomicAdd(&lds_sum[cb + o2], v.z);
        atomicAdd(&lds_sum[cb + o3], v.w);
        float sq = fmaf(v.w, v.w, fmaf(v.z, v.z, fmaf(v.y, v.y, v.x * v.x)));
        atomicAdd(&lds_sq[cls * 64 + lane], sq);
        if (lane == 0) atomicAdd(&lds_cnt[cls], 1.0f);
    };

    const int iters = N / TW;
    #pragma unroll 4
    for (int i = 0; i < iters; ++i) body(gw + i * TW);
    for (int r = iters * TW + gw; r < N; r += TW) body(r);  // tail (empty here)

    __syncthreads();

    // -------- flush --------
    const int  slot   = blockIdx.x % P;
    const bool direct = (nblk == P);

    // sums: un-swizzle and write natural [slot][k*DIM + d] layout
    for (int idx = t; idx < K_CLS * DIM; idx += TPB) {
        float val = lds_sum[idx ^ ((idx >> 5) & 3)];
        if (direct) psums[(size_t)slot * K_CLS * DIM + idx] = val;
        else        atomicAdd(&psums[(size_t)slot * K_CLS * DIM + idx], val);
    }

    // sq: reduce 64 lane-slots per class -> scalar; counts alongside
    {
        int k = t >> 4, i = t & 15;
        float p = lds_sq[k * 64 + i] + lds_sq[k * 64 + i + 16] +
                  lds_sq[k * 64 + i + 32] + lds_sq[k * 64 + i + 48];
        __syncthreads();
        lds_sq[k * 16 + i] = p;
        __syncthreads();
        if (t < K_CLS) {
            float ssum = 0.f;
            #pragma unroll
            for (int j = 0; j < 16; ++j) ssum += lds_sq[t * 16 + j];
            float cnt = lds_cnt[t];
            if (direct) {
                psq[t * P + slot]  = ssum;   // layout [K][P] for coalesced pass2
                pcnt[t * P + slot] = cnt;
            } else {
                atomicAdd(&psq[t * P + slot], ssum);
                atomicAdd(&pcnt[t * P + slot], cnt);
            }
        }
    }
}

// ---------------------------------------------------------------------------
// Pass 2: one block per class. Reduce P partials, emit centroid row + var.
// var[k] = sumsq[k]/cnt - ||mu_k||^2   (exact identity vs reference)
// ---------------------------------------------------------------------------
__global__ __launch_bounds__(1024) void fstat_pass2(
    const float* __restrict__ psums, const float* __restrict__ pcnt,
    const float* __restrict__ psq, float* __restrict__ out, int P)
{
    const int k = blockIdx.x;
    const int t = threadIdx.x;
    __shared__ float red[1024];
    __shared__ float sh_cnt, sh_sq;

    float cv = 0.f, qv = 0.f;
    for (int b = t; b < P; b += 1024) {
        cv += pcnt[k * P + b];
        qv += psq[k * P + b];
    }
    red[t] = cv; __syncthreads();
    for (int st = 512; st > 0; st >>= 1) { if (t < st) red[t] += red[t + st]; __syncthreads(); }
    if (t == 0) sh_cnt = red[0];
    __syncthreads();
    red[t] = qv; __syncthreads();
    for (int st = 512; st > 0; st >>= 1) { if (t < st) red[t] += red[t + st]; __syncthreads(); }
    if (t == 0) sh_sq = red[0];
    __syncthreads();

    // sums over partials: thread t handles (d = t&255), quarter q = t>>8 of b-range
    const int d = t & (DIM - 1);
    const int q = t >> 8;
    float acc = 0.f;
    for (int b = q; b < P; b += 4)
        acc += psums[(size_t)b * K_CLS * DIM + k * DIM + d];
    red[t] = acc; __syncthreads();

    if (t < DIM) {
        float sum = red[t] + red[t + 256] + red[t + 512] + red[t + 768];
        float cnt = fmaxf(sh_cnt, 1.f);
        float mu  = sum / cnt;
        out[k * DIM + t] = mu;
        red[t] = mu * mu;
    }
    __syncthreads();
    for (int st = 128; st > 0; st >>= 1) { if (t < st) red[t] += red[t + st]; __syncthreads(); }
    if (t == 0) {
        float cnt = fmaxf(sh_cnt, 1.f);
        out[K_CLS * DIM + k] = sh_sq / cnt - red[0];
    }
}

__global__ void fstat_zero(float* __restrict__ p, size_t n)
{
    size_t i = (size_t)blockIdx.x * blockDim.x + threadIdx.x;
    if (i < n) p[i] = 0.f;
}

extern "C" void kernel_launch(void* const* d_in, const int* in_sizes, int n_in,
                              void* d_out, int out_size, void* d_ws, size_t ws_size,
                              hipStream_t stream)
{
    const float* z = (const float*)d_in[0];
    const int*   c = (const int*)d_in[1];
    float* out = (float*)d_out;
    const int N = in_sizes[1];  // rows = B*S

    const size_t slot_f = (size_t)K_CLS * DIM;  // floats per sums slot
    int P = NBLK_MAX;
    size_t need = (P * slot_f + 2 * (size_t)K_CLS * P) * sizeof(float);
    if (need > ws_size) {
        P = (int)(ws_size / ((slot_f + 2 * K_CLS) * sizeof(float)));
        if (P < 1) P = 1;
        if (P > NBLK_MAX) P = NBLK_MAX;
    }

    float* psums = (float*)d_ws;
    float* pcnt  = psums + (size_t)P * slot_f;
    float* psq   = pcnt + (size_t)K_CLS * P;

    const int nblk = NBLK_MAX;
    if (P < nblk) {
        size_t zn = (size_t)P * slot_f + 2 * (size_t)K_CLS * P;
        fstat_zero<<<(int)((zn + 1023) / 1024), 1024, 0, stream>>>(psums, zn);
    }

    fstat_pass1<<<nblk, TPB, 0, stream>>>(z, c, psums, pcnt, psq, N, P, nblk);
    fstat_pass2<<<K_CLS, 1024, 0, stream>>>(psums, pcnt, psq, out, P);
}

// Round 2
// 39.530 us; speedup vs baseline: 6.0293x; 6.0293x over previous
//
#include <hip/hip_runtime.h>

#define K_CLS 64
#define DIM   256
#define TPB1  512      // 8 waves; wave w owns dims [32w, 32w+32)
#define MAXROWS 2048

typedef __attribute__((ext_vector_type(8)))  short short8;
typedef __attribute__((ext_vector_type(16))) float f32x16;

__device__ inline unsigned short f2bf(float x) {  // f32 -> bf16 RNE
    unsigned u = __float_as_uint(x);
    u += 0x7FFFu + ((u >> 16) & 1u);
    return (unsigned short)(u >> 16);
}

// ---------------------------------------------------------------------------
// Pass 1: per-block partial segment-sums via one-hot MFMA.
//   C1[k][d] = sum_{rows r in block, c[r]==k} z[r][d]      (bf16 in, f32 acc)
//   C2[k][d] = sum z[r][d]^2
// A-frag: onehot[m=class][kk=row], m = lane&31 (class tile 0/1), exact in bf16.
// B-frag: z[kk=row][n=dim],      n = lane&31.  kk = (lane>>5)*8 + i.
// ---------------------------------------------------------------------------
__global__ __launch_bounds__(TPB1) void fstat_p1(
    const float* __restrict__ z, const int* __restrict__ c,
    float* __restrict__ psum, float* __restrict__ psq, float* __restrict__ pcnt,
    int rows_per_blk, int nblk)
{
    __shared__ __align__(16) int cs[MAXROWS];
    __shared__ float lcnt[K_CLS];
    const int t   = threadIdx.x;
    const int blk = blockIdx.x;
    const int rb0 = blk * rows_per_blk;

    if (t < K_CLS) lcnt[t] = 0.f;
    __syncthreads();
    for (int r = t; r < rows_per_blk; r += TPB1) {
        int cv = c[rb0 + r];
        cs[r] = cv;
        atomicAdd(&lcnt[cv], 1.0f);     // 512 scattered lane-ops total: cheap
    }
    __syncthreads();

    const int wave = t >> 6;
    const int lane = t & 63;
    const int db   = wave * 32;         // this wave's dim base
    const int half = lane >> 5;         // k-half: rows +0..7 vs +8..15
    const int ln   = lane & 31;

    f32x16 aS0 = {}; f32x16 aS1 = {}; f32x16 aQ0 = {}; f32x16 aQ1 = {};

    const int nsteps = rows_per_blk >> 4;
    const size_t zo0 = (size_t)(rb0 + half * 8) * DIM + db + ln;

    float v[8];
    #pragma unroll
    for (int i = 0; i < 8; ++i) v[i] = z[zo0 + (size_t)i * DIM];

    for (int step = 0; step < nsteps; ++step) {
        float vn[8];
        if (step + 1 < nsteps) {
            const size_t zo = zo0 + (size_t)(step + 1) * 16 * DIM;
            #pragma unroll
            for (int i = 0; i < 8; ++i) vn[i] = z[zo + (size_t)i * DIM];
        }
        const int rb = step * 16 + half * 8;
        int4 c0 = *reinterpret_cast<const int4*>(&cs[rb]);
        int4 c1 = *reinterpret_cast<const int4*>(&cs[rb + 4]);
        int cl[8] = {c0.x, c0.y, c0.z, c0.w, c1.x, c1.y, c1.z, c1.w};

        short8 A0, A1, Bz, Bq;
        #pragma unroll
        for (int i = 0; i < 8; ++i) {
            A0[i] = (cl[i] == ln)      ? (short)0x3F80 : (short)0;
            A1[i] = (cl[i] == ln + 32) ? (short)0x3F80 : (short)0;
            Bz[i] = (short)f2bf(v[i]);
            Bq[i] = (short)f2bf(v[i] * v[i]);
        }
        aS0 = __builtin_amdgcn_mfma_f32_32x32x16_bf16(A0, Bz, aS0, 0, 0, 0);
        aS1 = __builtin_amdgcn_mfma_f32_32x32x16_bf16(A1, Bz, aS1, 0, 0, 0);
        aQ0 = __builtin_amdgcn_mfma_f32_32x32x16_bf16(A0, Bq, aQ0, 0, 0, 0);
        aQ1 = __builtin_amdgcn_mfma_f32_32x32x16_bf16(A1, Bq, aQ1, 0, 0, 0);
        if (step + 1 < nsteps) {
            #pragma unroll
            for (int i = 0; i < 8; ++i) v[i] = vn[i];
        }
    }

    // write partials: psum[blk][K][D], psq[blk][K][D]
    float* ps = psum + (size_t)blk * K_CLS * DIM;
    float* pq = psq  + (size_t)blk * K_CLS * DIM;
    #pragma unroll
    for (int r = 0; r < 16; ++r) {
        int row = (r & 3) + 8 * (r >> 2) + 4 * half;     // verified C/D mapping
        size_t o0 = (size_t)row * DIM + db + ln;
        size_t o1 = (size_t)(row + 32) * DIM + db + ln;
        ps[o0] = aS0[r]; ps[o1] = aS1[r];
        pq[o0] = aQ0[r]; pq[o1] = aQ1[r];
    }
    if (t < K_CLS) pcnt[(size_t)t * nblk + blk] = lcnt[t];
}

// ---------------------------------------------------------------------------
// Pass 2: block = (class k, dim-quarter q). Reduce nblk partials; write
// centroids; write quarter-partial of cnt*var to wvar.
// ---------------------------------------------------------------------------
__global__ __launch_bounds__(1024) void fstat_p2(
    const float* __restrict__ psum, const float* __restrict__ psq,
    const float* __restrict__ pcnt, float* __restrict__ out,
    float* __restrict__ wvar, float* __restrict__ wcnt, int nblk)
{
    const int k  = blockIdx.x >> 2;
    const int q  = blockIdx.x & 3;
    const int t  = threadIdx.x;
    const int d  = t & 63;      // dim within quarter
    const int sg = t >> 6;      // slot-group 0..15

    __shared__ float redS[16][64];
    __shared__ float redQ[16][64];
    __shared__ float sh_cnt;

    // ---- count reduction (flat LDS tree over redS) ----
    float* redF = &redS[0][0];
    float cpart = 0.f;
    for (int b = t; b < nblk; b += 1024) cpart += pcnt[(size_t)k * nblk + b];
    redF[t] = cpart; __syncthreads();
    for (int st = 512; st > 0; st >>= 1) {
        if (t < st) redF[t] += redF[t + st];
        __syncthreads();
    }
    if (t == 0) sh_cnt = redF[0];
    __syncthreads();

    // ---- sum / sumsq reduction over partial slots ----
    float s = 0.f, qq = 0.f;
    for (int b = sg; b < nblk; b += 16) {
        size_t o = ((size_t)b * K_CLS + k) * DIM + q * 64 + d;
        s  += psum[o];
        qq += psq[o];
    }
    redS[sg][d] = s;
    redQ[sg][d] = qq;
    __syncthreads();

    if (t < 64) {
        float su = 0.f, qu = 0.f;
        #pragma unroll
        for (int i = 0; i < 16; ++i) { su += redS[i][t]; qu += redQ[i][t]; }
        float cnt = fmaxf(sh_cnt, 1.f);
        float mu  = su / cnt;
        out[(size_t)k * DIM + q * 64 + t] = mu;
        float vp = qu - cnt * mu * mu;          // quarter partial of cnt*var
        #pragma unroll
        for (int off = 32; off > 0; off >>= 1) vp += __shfl_down(vp, off);
        if (t == 0) {
            wvar[k * 4 + q] = vp;
            if (q == 0) wcnt[k] = sh_cnt;
        }
    }
}

__global__ void fstat_p3(const float* __restrict__ wvar,
                         const float* __restrict__ wcnt, float* __restrict__ out)
{
    int k = threadIdx.x;
    float cnt = fmaxf(wcnt[k], 1.f);
    out[K_CLS * DIM + k] =
        (wvar[4 * k] + wvar[4 * k + 1] + wvar[4 * k + 2] + wvar[4 * k + 3]) / cnt;
}

extern "C" void kernel_launch(void* const* d_in, const int* in_sizes, int n_in,
                              void* d_out, int out_size, void* d_ws, size_t ws_size,
                              hipStream_t stream)
{
    const float* z = (const float*)d_in[0];
    const int*   c = (const int*)d_in[1];
    float* out = (float*)d_out;
    const int N = in_sizes[1];   // rows = B*S = 131072

    auto need = [](int nb) {
        return (size_t)nb * K_CLS * DIM * 2 * sizeof(float)   // psum+psq
             + (size_t)K_CLS * nb * sizeof(float)             // pcnt
             + (size_t)(K_CLS * 4 + K_CLS) * sizeof(float);   // wvar+wcnt
    };
    int nblk = 256;
    while (nblk > 64 &&
           (N % nblk != 0 || (N / nblk) % 16 != 0 || (N / nblk) > MAXROWS ||
            need(nblk) > ws_size))
        nblk >>= 1;

    const int rows_per_blk = N / nblk;

    float* psum = (float*)d_ws;
    float* psq  = psum + (size_t)nblk * K_CLS * DIM;
    float* pcnt = psq  + (size_t)nblk * K_CLS * DIM;
    float* wvar = pcnt + (size_t)K_CLS * nblk;
    float* wcnt = wvar + K_CLS * 4;

    fstat_p1<<<nblk, TPB1, 0, stream>>>(z, c, psum, psq, pcnt, rows_per_blk, nblk);
    fstat_p2<<<K_CLS * 4, 1024, 0, stream>>>(psum, psq, pcnt, out, wvar, wcnt, nblk);
    fstat_p3<<<1, K_CLS, 0, stream>>>(wvar, wcnt, out);
}